// Round 5
// baseline (4942.473 us; speedup 1.0000x reference)
//
#include <hip/hip_runtime.h>

typedef unsigned short u16;
typedef unsigned int u32;

#define NKPT 80
#define LSPIRAL 41

__device__ __forceinline__ float b2f(u16 v) {
  return __uint_as_float(((u32)v) << 16);
}
__device__ __forceinline__ u16 f2b(float f) {
  u32 u = __float_as_uint(f);
  return (u16)((u + 0x7FFFu + ((u >> 16) & 1u)) >> 16);
}

// One wave computes RT rows x CT output channels. Lanes split K (64-way),
// shuffle-reduce at the end. All loads coalesced (lane -> adjacent k).
// Inputs (per reference) are FLOAT32. Intermediates stored as bf16 (u16).
// LH=1: H is u16 bf16 storage; LH=0: H is float32.
// SO=1: out is u16 bf16 storage; SO=0: out is float32 (final output).
// GATHER=1: H is (128*80, C), C = 1<<LOG2C; row r = b*80+n reads
//   H[(b*80 + clamp(idx[n, k>>LOG2C]))*C + (k & (C-1))].
template <int RT, int CT, int GATHER, int LOG2C, int LH, int SO>
__global__ __launch_bounds__(256)
void layer_k(const void* __restrict__ Hv, const float* __restrict__ W,
             const float* __restrict__ bias, const int* __restrict__ idx,
             void* __restrict__ outv, int nRows, int nCh, int K, int act) {
  const u16* Hu = (const u16*)Hv;
  const float* Hf = (const float*)Hv;
  const int lane = threadIdx.x & 63;
  const int wid = blockIdx.x * 4 + (threadIdx.x >> 6);
  const int chTiles = nCh / CT;
  const int r0 = (wid / chTiles) * RT;
  const int o0 = (wid % chTiles) * CT;
  if (r0 >= nRows) return;

  float acc[RT][CT];
#pragma unroll
  for (int i = 0; i < RT; i++)
#pragma unroll
    for (int j = 0; j < CT; j++) acc[i][j] = 0.f;

  const float* wp[CT];
#pragma unroll
  for (int j = 0; j < CT; j++) wp[j] = W + (size_t)(o0 + j) * K;

  int bBase[RT];
  const int* ip[RT];
#pragma unroll
  for (int i = 0; i < RT; i++) {
    const int r = r0 + i;
    if (GATHER) {
      const int b = r / NKPT;
      const int n = r - b * NKPT;
      bBase[i] = (b * NKPT) << LOG2C;
      ip[i] = idx + n * LSPIRAL;
    } else {
      bBase[i] = r * K;  // direct row base
    }
  }

  const int iters = K >> 6;
  for (int t = 0; t < iters; ++t) {
    const int k = (t << 6) | lane;
    float wv[CT];
#pragma unroll
    for (int j = 0; j < CT; j++) wv[j] = wp[j][k];
    float hv[RT];
    if (GATHER) {
      const int l = k >> LOG2C;
      const int c = k & ((1 << LOG2C) - 1);
#pragma unroll
      for (int i = 0; i < RT; i++) {
        int J = ip[i][l];
        J = min(max(J, 0), NKPT - 1);  // defensive: stay in-bounds
        const int a = bBase[i] + (J << LOG2C) + c;
        hv[i] = LH ? b2f(Hu[a]) : Hf[a];
      }
    } else {
#pragma unroll
      for (int i = 0; i < RT; i++) {
        const int a = bBase[i] + k;
        hv[i] = LH ? b2f(Hu[a]) : Hf[a];
      }
    }
#pragma unroll
    for (int i = 0; i < RT; i++)
#pragma unroll
      for (int j = 0; j < CT; j++) acc[i][j] = fmaf(hv[i], wv[j], acc[i][j]);
  }

#pragma unroll
  for (int i = 0; i < RT; i++)
#pragma unroll
    for (int j = 0; j < CT; j++) {
      float v = acc[i][j];
#pragma unroll
      for (int off = 32; off > 0; off >>= 1) v += __shfl_down(v, off, 64);
      acc[i][j] = v;  // lane 0 holds the sum
    }

  if (lane == 0) {
#pragma unroll
    for (int i = 0; i < RT; i++)
#pragma unroll
      for (int j = 0; j < CT; j++) {
        float v = acc[i][j] + bias[o0 + j];
        if (act) v = v > 0.f ? v : (expf(v) - 1.f);
        const size_t oi = (size_t)(r0 + i) * nCh + (o0 + j);
        if (SO) ((u16*)outv)[oi] = f2b(v);
        else ((float*)outv)[oi] = v;
      }
  }
}

extern "C" void kernel_launch(void* const* d_in, const int* in_sizes, int n_in,
                              void* d_out, int out_size, void* d_ws, size_t ws_size,
                              hipStream_t stream) {
  const float* x  = (const float*)d_in[0];
  const float* W0 = (const float*)d_in[1];
  const float* b0 = (const float*)d_in[2];
  const float* W1 = (const float*)d_in[3];
  const float* b1 = (const float*)d_in[4];
  const float* W2 = (const float*)d_in[5];
  const float* b2 = (const float*)d_in[6];
  const float* W3 = (const float*)d_in[7];
  const float* b3 = (const float*)d_in[8];
  const float* W4 = (const float*)d_in[9];
  const float* b4 = (const float*)d_in[10];
  const int* idx = (const int*)d_in[11];
  float* out = (float*)d_out;

  char* ws = (char*)d_ws;
  u16* hA = (u16*)(ws);             // h0 (128x20480), later h2 (10240x128)
  u16* hB = (u16*)(ws + 5242880);   // h1 (10240x256), later h3 (10240x64)
  // peak workspace: 10,485,760 B (bf16 intermediates)

  // L0: h0 = x @ W0^T + b0  (rows=128, ch=20480, K=1024), no act
  layer_k<4, 8, 0, 0, 0, 1><<<20480, 256, 0, stream>>>(
      x, W0, b0, idx, hA, 128, 20480, 1024, 0);

  // L1: rows=10240, ch=256, K=41*256=10496, gather C=256, ELU
  layer_k<4, 8, 1, 8, 1, 1><<<20480, 256, 0, stream>>>(
      hA, W1, b1, idx, hB, 10240, 256, 10496, 1);

  // L2: ch=128, K=10496, gather C=256, ELU
  layer_k<4, 8, 1, 8, 1, 1><<<10240, 256, 0, stream>>>(
      hB, W2, b2, idx, hA, 10240, 128, 10496, 1);

  // L3: ch=64, K=41*128=5248, gather C=128, ELU
  layer_k<4, 8, 1, 7, 1, 1><<<5120, 256, 0, stream>>>(
      hA, W3, b3, idx, hB, 10240, 64, 5248, 1);

  // L4: ch=2, K=41*64=2624, gather C=64, no act -> fp32 out (128,80,2)
  layer_k<4, 2, 1, 6, 1, 0><<<640, 256, 0, stream>>>(
      hB, W4, b4, idx, out, 10240, 2, 2624, 0);
}

// Round 6
// 400.513 us; speedup vs baseline: 12.3403x; 12.3403x over previous
//
#include <hip/hip_runtime.h>

typedef unsigned short u16;
typedef unsigned int u32;
typedef __bf16 bf16;
typedef __attribute__((ext_vector_type(8))) __bf16 bf16x8;
typedef __attribute__((ext_vector_type(4))) float f32x4;
typedef __attribute__((ext_vector_type(8))) float f32x8;
typedef __attribute__((ext_vector_type(4))) u16 u16x4;

#define NKPT 80
#define LSPIRAL 41

__device__ __forceinline__ float b2f(u16 v) { return __uint_as_float(((u32)v) << 16); }
__device__ __forceinline__ u16 f2b(float f) {
  u32 u = __float_as_uint(f);
  return (u16)((u + 0x7FFFu + ((u >> 16) & 1u)) >> 16);
}

__device__ __forceinline__ void gload_lds16(const u16* g, u16* l) {
  __builtin_amdgcn_global_load_lds(
      (const __attribute__((address_space(1))) unsigned int*)g,
      (__attribute__((address_space(3))) unsigned int*)l,
      16, 0, 0);
}

// fp32 -> bf16(u16) elementwise, 4 elems/thread. n % 4 == 0.
__global__ __launch_bounds__(256)
void cvt_f2b(const float* __restrict__ src, u16* __restrict__ dst, int n4) {
  const int i = blockIdx.x * 256 + threadIdx.x;
  if (i >= n4) return;
  const f32x4 v = *(const f32x4*)(src + i * 4);
  u16x4 o;
#pragma unroll
  for (int t = 0; t < 4; t++) o[t] = f2b(v[t]);
  *(u16x4*)(dst + i * 4) = o;
}

__global__ __launch_bounds__(256)
void zero_f32(float* __restrict__ p, int n4) {
  const int i = blockIdx.x * 256 + threadIdx.x;
  if (i < n4) ((f32x4*)p)[i] = (f32x4){0.f, 0.f, 0.f, 0.f};
}

// NT GEMM, MFMA 16x16x32 bf16, BK=64, 256 threads (4 waves, 2x2 wave grid).
// A source: bf16(u16). GATHER=1: A is (128*80, C), C=1<<LOG2C, row r=b*80+n
//   reads A[(b*80 + idx[n, k>>LOG2C])*C + (k & (C-1))]; staged via global_load_lds.
// B source: BCVT=0 -> bf16(u16) via global_load_lds; BCVT=1 -> fp32 with
//   register round-trip + convert.
// OUTM=0: direct bf16(u16) out + bias (+ELU). OUTM=1: atomicAdd fp32 P.
template <int BM, int BN, int GATHER, int LOG2C, int OUTM, int BCVT>
__global__ __launch_bounds__(256)
void gemm_sp(const u16* __restrict__ A, const void* __restrict__ Wt,
             const int* __restrict__ gidx, float* __restrict__ P,
             u16* __restrict__ Out, const float* __restrict__ bias, int act,
             int N, int K, int itersTotal, int itersPerSplit) {
  constexpr int BK = 64;
  constexpr int WN = BN / 2;
  constexpr int TN = WN / 16;
  constexpr int IA = BM / 32;
  constexpr int IB = BN / 32;
  constexpr int CMASK = (1 << LOG2C) - 1;

  __shared__ u16 As[BM * BK];
  __shared__ u16 Bs[BN * BK];
  __shared__ int idx_s[GATHER ? NKPT * LSPIRAL : 1];

  const int tid = threadIdx.x;
  const int lane = tid & 63;
  const int wave = tid >> 6;

  if (GATHER) {
    for (int t = tid; t < NKPT * LSPIRAL; t += 256) idx_s[t] = gidx[t];
  }

  const int bm0 = blockIdx.x * BM;
  const int bn0 = blockIdx.y * BN;
  const int split = blockIdx.z;
  const int it0 = split * itersPerSplit;
  const int itEnd = min(itersTotal, it0 + itersPerSplit);

  // Wave-chunk q = 8 rows x 64 k (1024 B). Lane rIn*8+cl handles row rIn,
  // k-chunk cl; DMA lands its 16 B at chunkBase + lane*16 (m104/m108).
  const int rIn = lane >> 3;
  const int koff = (lane & 7) * 8;

  int aBase[IA];
  const int* aIdxP[IA];
  const u16* aPtr[IA];
  u16* aDst[IA];
#pragma unroll
  for (int i = 0; i < IA; i++) {
    const int q = i * 4 + wave;
    const int r = bm0 + q * 8 + rIn;
    aDst[i] = As + q * 512;
    if (GATHER) {
      const int b = (r * 52429) >> 22;  // r/80 exact for r<10240
      const int n = r - b * 80;
      aBase[i] = (b * NKPT) << LOG2C;
      aIdxP[i] = idx_s + n * LSPIRAL;
    } else {
      aPtr[i] = A + (size_t)r * K + koff;
    }
  }
  const u16* bPtrH[IB];      // bf16 source
  const float* bPtrF[IB];    // fp32 source
  u16* bDst[IB];
#pragma unroll
  for (int i = 0; i < IB; i++) {
    const int q = i * 4 + wave;
    const int o = bn0 + q * 8 + rIn;
    bDst[i] = Bs + q * 512;
    if (BCVT) bPtrF[i] = (const float*)Wt + (size_t)o * K + koff;
    else bPtrH[i] = (const u16*)Wt + (size_t)o * K + koff;
  }

  f32x4 acc[4][TN];
#pragma unroll
  for (int i = 0; i < 4; i++)
#pragma unroll
    for (int j = 0; j < TN; j++) acc[i][j] = (f32x4){0.f, 0.f, 0.f, 0.f};

  const int wm = (wave >> 1) * 64;
  const int wn = (wave & 1) * WN;
  const int m15 = lane & 15;
  const int quad = lane >> 4;

  __syncthreads();  // idx_s ready; also first-iter WAR no-op

  for (int it = it0; it < itEnd; ++it) {
    const int k0 = it * BK;

    bf16x8 bw[IB];
    if (BCVT) {  // load fp32 B and convert in regs (before LDS writes)
#pragma unroll
      for (int i = 0; i < IB; i++) {
        const f32x8 v = *(const f32x8*)(bPtrF[i] + k0);
#pragma unroll
        for (int t = 0; t < 8; t++) bw[i][t] = (bf16)v[t];
      }
    }

    // stage A via LDS-DMA
    if (GATHER) {
      const int l = k0 >> LOG2C;            // tile-uniform spiral position
      const int cb = (k0 & CMASK) + koff;
#pragma unroll
      for (int i = 0; i < IA; i++) {
        int J = aIdxP[i][l];
        J = min(max(J, 0), NKPT - 1);
        gload_lds16(A + aBase[i] + (J << LOG2C) + cb, aDst[i]);
      }
    } else {
#pragma unroll
      for (int i = 0; i < IA; i++) gload_lds16(aPtr[i] + k0, aDst[i]);
    }
    // stage B
    if (BCVT) {
#pragma unroll
      for (int i = 0; i < IB; i++) *(bf16x8*)(bDst[i] + lane * 8) = bw[i];
    } else {
#pragma unroll
      for (int i = 0; i < IB; i++) gload_lds16(bPtrH[i] + k0, bDst[i]);
    }

    __syncthreads();  // vmcnt+lgkm drain -> tiles valid

#pragma unroll
    for (int kk = 0; kk < 2; kk++) {
      const int fko = kk * 32 + quad * 8;
      bf16x8 av[4], bv[TN];
#pragma unroll
      for (int i = 0; i < 4; i++)
        av[i] = *(const bf16x8*)(As + (wm + i * 16 + m15) * BK + fko);
#pragma unroll
      for (int j = 0; j < TN; j++)
        bv[j] = *(const bf16x8*)(Bs + (wn + j * 16 + m15) * BK + fko);
#pragma unroll
      for (int i = 0; i < 4; i++)
#pragma unroll
        for (int j = 0; j < TN; j++)
          acc[i][j] = __builtin_amdgcn_mfma_f32_16x16x32_bf16(av[i], bv[j], acc[i][j], 0, 0, 0);
    }
    __syncthreads();  // WAR before next stage
  }

  // C/D layout: col = lane&15, row = quad*4 + reg  (m89/m91-verified)
#pragma unroll
  for (int i = 0; i < 4; i++) {
    const int r = bm0 + wm + i * 16 + quad * 4;
#pragma unroll
    for (int j = 0; j < TN; j++) {
      const int c = bn0 + wn + j * 16 + m15;
      if (OUTM == 0) {
        const float bv = bias[c];
#pragma unroll
        for (int t = 0; t < 4; t++) {
          float v = acc[i][j][t] + bv;
          if (act) v = v > 0.f ? v : (__expf(v) - 1.f);
          Out[(size_t)(r + t) * N + c] = f2b(v);
        }
      } else {
#pragma unroll
        for (int t = 0; t < 4; t++)
          atomicAdd(P + (size_t)(r + t) * N + c, acc[i][j][t]);
      }
    }
  }
}

// bias (+ELU) on accumulated fp32 P -> bf16(u16)
__global__ __launch_bounds__(256)
void epilogue_k(const float* __restrict__ P, const float* __restrict__ bias,
                u16* __restrict__ out, int MN, int N, int act) {
  const int i4 = (blockIdx.x * 256 + threadIdx.x) * 4;
  if (i4 >= MN) return;
  const f32x4 acc = *(const f32x4*)(P + i4);
  const int col = i4 % N;
  u16x4 o;
#pragma unroll
  for (int t = 0; t < 4; t++) {
    float v = acc[t] + bias[col + t];
    if (act) v = v > 0.f ? v : (__expf(v) - 1.f);
    o[t] = f2b(v);
  }
  *(u16x4*)(out + i4) = o;
}

// Last layer: O=2, K=41*64. One wave per row; lane = channel within 64.
__global__ __launch_bounds__(256)
void final_k(const u16* __restrict__ h3, const float* __restrict__ W4,
             const float* __restrict__ b4, const int* __restrict__ gidx,
             float* __restrict__ out) {
  const int lane = threadIdx.x & 63;
  const int wave = threadIdx.x >> 6;
  const int r = blockIdx.x * 4 + wave;  // < 10240
  const int b = r / 80;
  const int n = r - b * 80;
  const int* ip = gidx + n * LSPIRAL;
  const float* w0 = W4 + lane;
  const float* w1 = W4 + 2624 + lane;
  const u16* hb = h3 + b * (NKPT * 64) + lane;
  float a0 = 0.f, a1 = 0.f;
  for (int l = 0; l < LSPIRAL; l++) {
    int J = ip[l];
    J = min(max(J, 0), NKPT - 1);
    const float hv = b2f(hb[J * 64]);
    a0 += hv * w0[l * 64];
    a1 += hv * w1[l * 64];
  }
#pragma unroll
  for (int off = 32; off > 0; off >>= 1) {
    a0 += __shfl_down(a0, off, 64);
    a1 += __shfl_down(a1, off, 64);
  }
  if (lane == 0) {
    out[r * 2 + 0] = a0 + b4[0];
    out[r * 2 + 1] = a1 + b4[1];
  }
}

extern "C" void kernel_launch(void* const* d_in, const int* in_sizes, int n_in,
                              void* d_out, int out_size, void* d_ws, size_t ws_size,
                              hipStream_t stream) {
  const float* x  = (const float*)d_in[0];
  const float* W0 = (const float*)d_in[1];
  const float* b0 = (const float*)d_in[2];
  const float* W1 = (const float*)d_in[3];
  const float* b1 = (const float*)d_in[4];
  const float* W2 = (const float*)d_in[5];
  const float* b2 = (const float*)d_in[6];
  const float* W3 = (const float*)d_in[7];
  const float* b3 = (const float*)d_in[8];
  const float* W4 = (const float*)d_in[9];
  const float* b4 = (const float*)d_in[10];
  const int* idx = (const int*)d_in[11];
  float* out = (float*)d_out;

  char* ws = (char*)d_ws;
  u16* hA  = (u16*)(ws);                  // 5,242,880 B  (h0, then h2)
  u16* hB  = (u16*)(ws + 5242880);        // 5,242,880 B  (h1, then h3)
  u16* xb  = (u16*)(ws + 10485760);       //   262,144 B  (x bf16)
  u16* W1b = (u16*)(ws + 10747904);       // 5,373,952 B
  u16* W2b = (u16*)(ws + 16121856);       // 2,686,976 B
  u16* W3b = (u16*)(ws + 18808832);       //   671,744 B
  float* P = (float*)(ws + 19480576);     // 10,485,760 B -> end 29,966,336

  const bool full = ws_size >= (size_t)29966336;

  if (full) {
    // Pre-convert x and W1..W3 to bf16
    cvt_f2b<<<128, 256, 0, stream>>>(x, xb, 32768);
    cvt_f2b<<<2624, 256, 0, stream>>>(W1, W1b, 671744);
    cvt_f2b<<<1312, 256, 0, stream>>>(W2, W2b, 335872);
    cvt_f2b<<<328, 256, 0, stream>>>(W3, W3b, 83968);

    // L0: h0 = xb @ W0^T + b0 (M=128, N=20480, K=1024), B cvt in staging
    gemm_sp<128, 64, 0, 0, 0, 1><<<dim3(1, 320, 1), 256, 0, stream>>>(
        xb, W0, idx, nullptr, hA, b0, 0, 20480, 1024, 16, 16);

    // L1: M=10240 N=256 K=10496, split 3 -> 480 blocks
    zero_f32<<<2560, 256, 0, stream>>>(P, 655360);
    gemm_sp<128, 128, 1, 8, 1, 0><<<dim3(80, 2, 3), 256, 0, stream>>>(
        hA, W1b, idx, P, nullptr, nullptr, 0, 256, 10496, 164, 55);
    epilogue_k<<<2560, 256, 0, stream>>>(P, b1, hB, 2621440, 256, 1);

    // L2: N=128 K=10496, split 6 -> 480 blocks
    zero_f32<<<1280, 256, 0, stream>>>(P, 327680);
    gemm_sp<128, 128, 1, 8, 1, 0><<<dim3(80, 1, 6), 256, 0, stream>>>(
        hB, W2b, idx, P, nullptr, nullptr, 0, 128, 10496, 164, 28);
    epilogue_k<<<1280, 256, 0, stream>>>(P, b2, hA, 1310720, 128, 1);

    // L3: N=64 K=5248, split 6 -> 480 blocks
    zero_f32<<<640, 256, 0, stream>>>(P, 163840);
    gemm_sp<128, 64, 1, 7, 1, 0><<<dim3(80, 1, 6), 256, 0, stream>>>(
        hA, W3b, idx, P, nullptr, nullptr, 0, 64, 5248, 82, 14);
    epilogue_k<<<640, 256, 0, stream>>>(P, b3, hB, 655360, 64, 1);
  } else {
    // Fallback (<= 10.5 MB ws): cvt x only into hB tail? Not enough room —
    // use in-staging conversion everywhere and fp32 x via cvt into hA start.
    cvt_f2b<<<128, 256, 0, stream>>>(x, hB, 32768);  // xb in hB temporarily
    gemm_sp<128, 64, 0, 0, 0, 1><<<dim3(1, 320, 1), 256, 0, stream>>>(
        hB, W0, idx, nullptr, hA, b0, 0, 20480, 1024, 16, 16);
    gemm_sp<128, 128, 1, 8, 0, 1><<<dim3(80, 2, 1), 256, 0, stream>>>(
        hA, W1, idx, nullptr, hB, b1, 1, 256, 10496, 164, 164);
    gemm_sp<128, 128, 1, 8, 0, 1><<<dim3(80, 1, 1), 256, 0, stream>>>(
        hB, W2, idx, nullptr, hA, b2, 1, 128, 10496, 164, 164);
    gemm_sp<128, 64, 1, 7, 0, 1><<<dim3(80, 1, 1), 256, 0, stream>>>(
        hA, W3, idx, nullptr, hB, b3, 1, 64, 5248, 82, 82);
  }

  // L4 -> fp32 out (128,80,2)
  final_k<<<2560, 256, 0, stream>>>(hB, W4, b4, idx, out);
}